// Round 10
// baseline (682.190 us; speedup 1.0000x reference)
//
#include <hip/hip_runtime.h>
#include <cstdint>
#include <cstddef>

// ---------------------------------------------------------------------------
// TGNN fused pipeline v17 = v16 with:
//  (A) h2 chunk DOUBLE-BUFFERED -> 1 barrier per nc (was 2). Parity proof:
//      between consecutive barriers writes are epi(nc)->chunk[nc&1] and
//      epi(nc+1)->chunk[(nc+1)&1]; reads are p2(nc)->chunk[nc&1]; same-parity
//      reuse is always 2 barriers apart. Requires no-pad strides + XOR swizzle
//      (T2): hbuf stride 384 elems (768B, 6x128 closure), chunk stride 128
//      (256B), off ^= (row&7)<<4 on full byte offset (strides %128==0 so the
//      swizzle is bijective; bank spread = old padded 4-way). LDS total
//      49152+32768 = 81920 B = EXACTLY 2 blocks/CU (allocator exact).
//  (B) embed converted to 32x32 + asm gload/VMW pipeline: aw frags loaded
//      once, reused for a1 AND a2 (6 gloads); p1's 6-load prologue issued
//      BEFORE embed MFMAs (hidden under entire embed). VMW counts extend
//      v16's verified schedule: 12 out -> 10/8/6 in embed -> p1 enters at
//      steady VMW(6).
// v16 postmortem: seg 194, bank-conflicts 13.9M->1.1M, matrix floor ~62us;
// ~40% of block time = barrier skew + embed's unpipelined compiler phase.
// Barriers/block 10 -> 6.
// Tripwires: Occupancy ~20 (if ~10, LDS didn't fit 2 blocks -> revert);
// absmax 0 (swizzle consistency); WRITE_SIZE exactly 6250KB.
// ---------------------------------------------------------------------------

typedef __bf16 bf16;
typedef __attribute__((ext_vector_type(8))) __bf16 bf16x8;
typedef __attribute__((ext_vector_type(4))) __bf16 bf16x4;
typedef __attribute__((ext_vector_type(4))) float floatx4;
typedef __attribute__((ext_vector_type(16))) float floatx16;

#define GRP 100
#define NWIN 3125        // 200000 rows / 64

// packed-ws element offsets (bf16 elements)
#define WOFF_AW 0
#define WOFF_BW 8192
#define WOFF_P1 12288
#define WOFF_P2 208896
#define WOFF_P3 339968
#define WOFF_F1 602112
#define WOFF_F2 1126400
#define WOFF_HS 1142784          // hsum [6250][256] f32 (2 bf16 elems each)

#define LSTR_MS 264

// byte-offset XOR swizzle; valid because all strides are multiples of 128B
#define SWZ(row, off) ((off) ^ (((row) & 7) << 4))

static __device__ __forceinline__ floatx4 mfma16(bf16x8 a, bf16x8 b, floatx4 c) {
  return __builtin_amdgcn_mfma_f32_16x16x32_bf16(a, b, c, 0, 0, 0);
}
static __device__ __forceinline__ floatx16 mfma32(bf16x8 a, bf16x8 b, floatx16 c) {
  return __builtin_amdgcn_mfma_f32_32x32x16_bf16(a, b, c, 0, 0, 0);
}

static __device__ __forceinline__ void gload(floatx4& d, const bf16* p) {
  asm volatile("global_load_dwordx4 %0, %1, off" : "=v"(d) : "v"(p));
}
static __device__ __forceinline__ bf16x8 bc8(floatx4 v) {
  return __builtin_bit_cast(bf16x8, v);
}
static __device__ __forceinline__ bf16x8 ldsr(const bf16* b, int byteoff) {
  return *(const bf16x8*)((const char*)b + byteoff);
}

#define VMW(N)                                         \
  do {                                                 \
    asm volatile("s_waitcnt vmcnt(" #N ")");           \
    __builtin_amdgcn_sched_barrier(0);                 \
  } while (0)

#define SYNCL()                                        \
  do {                                                 \
    asm volatile("s_waitcnt lgkmcnt(0)" ::: "memory"); \
    __builtin_amdgcn_s_barrier();                      \
  } while (0)

// ---------------------------------------------------------------------------
// Coalesced weight repack. newf layout (aw/bw/p1w/p2w): 1KB chunk per
// (g=32-col group, kt, h=k-half16): elem(c,k16) at (c+32*(k16>>3))*8+(k16&7),
// chunk = ((g*KT+kt)*2+h)*512. Old layout (p3w/f1w/f2w) unchanged.
// ---------------------------------------------------------------------------
__global__ __launch_bounds__(256) void pack_lds(
    const float* __restrict__ aw, const float* __restrict__ bw,
    const float* __restrict__ p1w, const float* __restrict__ p2w,
    const float* __restrict__ p3w, const float* __restrict__ f1w,
    const float* __restrict__ f2w, bf16* __restrict__ wpk) {
  __shared__ float t[32][65];
  const int tid = threadIdx.x;
  int b = blockIdx.x;

  if (b < 550) {
    const float* src; int dstoff, K, N, tt;
    bool newf = false;
    if (b < 4)        { src = aw;  dstoff = WOFF_AW; K = 64;   N = 128;  tt = b;       newf = true; }
    else if (b < 6)   { src = bw;  dstoff = WOFF_BW; K = 32;   N = 128;  tt = b - 4;   newf = true; }
    else if (b < 102) { src = p1w; dstoff = WOFF_P1; K = 384;  N = 512;  tt = b - 6;   newf = true; }
    else if (b < 166) { src = p2w; dstoff = WOFF_P2; K = 512;  N = 256;  tt = b - 102; newf = true; }
    else if (b < 294) { src = p3w; dstoff = WOFF_P3; K = 256;  N = 1024; tt = b - 166; }
    else              { src = f1w; dstoff = WOFF_F1; K = 1024; N = 512;  tt = b - 294; }
    const int KT = K >> 5;
    const int kt = tt % KT;
    const int n0 = (tt / KT) * 64;
    for (int i = tid; i < 2048; i += 256) {
      int r = i >> 6, c = i & 63;
      t[r][c] = src[(size_t)(kt * 32 + r) * N + n0 + c];
    }
    __syncthreads();
    if (newf) {
      const int cpp = tid & 63, rb = tid >> 6;      // col-in-64, k-oct
      const int g = (n0 >> 5) + (cpp >> 5);
      const int c = cpp & 31;
      bf16x8 v;
#pragma unroll
      for (int i = 0; i < 8; ++i) v[i] = (bf16)t[rb * 8 + i][cpp];
      *(bf16x8*)(wpk + dstoff +
                 (((size_t)g * KT + kt) * 2 + (rb >> 1)) * 512 +
                 (c + 32 * (rb & 1)) * 8) = v;
    } else {
      const int nc = n0 >> 7, nl0 = n0 & 127;
      bf16* dst = wpk + dstoff + ((size_t)(nc * KT + kt) * 128 + nl0) * 32;
      int o = tid * 8;
      int nl = o >> 5, kk = o & 31;
      bf16x8 v;
#pragma unroll
      for (int i = 0; i < 8; ++i) v[i] = (bf16)t[kk + i][nl];
      *(bf16x8*)(dst + nl * 32 + kk) = v;
    }
  } else {
    const int kt = b - 550;
    for (int i = tid; i < 1024; i += 256) {
      int r = i >> 5, c = i & 31;
      t[r][c] = f2w[(size_t)(kt * 32 + r) * 32 + c];
    }
    __syncthreads();
    if (tid < 128) {
      int o = tid * 8;
      int nl = o >> 5, kk = o & 31;
      bf16x8 v;
#pragma unroll
      for (int i = 0; i < 8; ++i) v[i] = (bf16)t[kk + i][nl];
      *(bf16x8*)(wpk + WOFF_F2 + kt * 1024 + nl * 32 + kk) = v;
    }
  }
}

// ---------------------------------------------------------------------------
// seg_kernel: one block per 64-row WINDOW. Embed+p1+p2 all on 32x32x16 with
// the asm B-pipeline. hbuf [64][384] swizzled (49152 B); dbuf 32768 B hosts
// pairs (stride 384B, swizzled) then 2x h2 chunks [64][128] swizzled.
// 6 barriers/block. Masked row-sums -> hsum f32.
// ---------------------------------------------------------------------------
__global__ __launch_bounds__(256, 2) void seg_kernel(
    const float* __restrict__ pairs, const float* __restrict__ ab,
    const float* __restrict__ bb, const float* __restrict__ p1b,
    const float* __restrict__ p2b, const bf16* __restrict__ wpk,
    float* __restrict__ hsum) {
  __shared__ __align__(16) bf16 hbuf[64 * 384];
  __shared__ __align__(16) bf16 dbuf[2 * 64 * 128];

  const int tid = threadIdx.x;
  const int w = tid >> 6;
  const int lane = tid & 63;
  const int l31 = lane & 31;
  const int hi = lane >> 5;
  const int hib = hi * 16;        // byte offset of k-oct within frag col range
  const int ln8 = lane * 8;       // elems
  const int blk = blockIdx.x;

  // ---- stage pairs window [64,160] fp32 -> bf16 dbuf (stride 384B, swz) ----
  {
    const float4* src = (const float4*)(pairs + (size_t)blk * (64 * 160));
    for (int i = tid; i < 64 * 40; i += 256) {
      int row = i / 40;
      int c4 = i - row * 40;
      float4 v = src[i];
      bf16x4 o = {(bf16)v.x, (bf16)v.y, (bf16)v.z, (bf16)v.w};
      *(bf16x4*)((char*)dbuf + SWZ(row, row * 384 + c4 * 8)) = o;
    }
  }

  // ---- preload ALL biases into registers (no vmem inside asm phases) ----
  float abv = ab[w * 32 + l31];
  float bbv = bb[w * 32 + l31];
  float p1bv[4], p2bv[2];
#pragma unroll
  for (int nc = 0; nc < 4; ++nc) p1bv[nc] = p1b[nc * 128 + w * 32 + l31];
  p2bv[0] = p2b[w * 32 + l31];
  p2bv[1] = p2b[(w + 4) * 32 + l31];
  asm volatile("" : "+v"(abv), "+v"(bbv), "+v"(p1bv[0]), "+v"(p1bv[1]),
                    "+v"(p1bv[2]), "+v"(p1bv[3]), "+v"(p2bv[0]), "+v"(p2bv[1]));

  SYNCL();   // pairs visible; no vmem outstanding

  const floatx16 fz16 = {0.f, 0.f, 0.f, 0.f, 0.f, 0.f, 0.f, 0.f,
                         0.f, 0.f, 0.f, 0.f, 0.f, 0.f, 0.f, 0.f};
  floatx4 p1r0[4], p1r1[4];   // p1 B slots (4-slot, 3-kt lead)
  floatx4 p2r[3][4];          // p2 B slots (3-slot)
  floatx16 acc2[2];
  floatx16 acc3[4];

  // ---- issue embed B (6) + p1 nc=0 prologue (6): 12 outstanding ----
  floatx4 eb[6];
  gload(eb[0], wpk + WOFF_AW + ((size_t)(w * 2 + 0) * 2 + 0) * 512 + ln8);
  gload(eb[1], wpk + WOFF_AW + ((size_t)(w * 2 + 0) * 2 + 1) * 512 + ln8);
  gload(eb[2], wpk + WOFF_AW + ((size_t)(w * 2 + 1) * 2 + 0) * 512 + ln8);
  gload(eb[3], wpk + WOFF_AW + ((size_t)(w * 2 + 1) * 2 + 1) * 512 + ln8);
  gload(eb[4], wpk + WOFF_BW + ((size_t)(w * 2 + 0)) * 512 + ln8);
  gload(eb[5], wpk + WOFF_BW + ((size_t)(w * 2 + 1)) * 512 + ln8);
#pragma unroll
  for (int q = 0; q < 3; ++q) {
    gload(p1r0[q], wpk + WOFF_P1 + (((size_t)w * 12 + q) * 2 + 0) * 512 + ln8);
    gload(p1r1[q], wpk + WOFF_P1 + (((size_t)w * 12 + q) * 2 + 1) * 512 + ln8);
  }

  // ---------------- embed: a1 / a2 / be -> hbuf (32x32, swz) ----------------
  {
    bf16x8 af[8];   // [rg*4 + kt*2 + h]
#pragma unroll
    for (int rg = 0; rg < 2; ++rg)
#pragma unroll
      for (int kt = 0; kt < 2; ++kt)
#pragma unroll
        for (int h = 0; h < 2; ++h) {
          int row = rg * 32 + l31;
          af[rg * 4 + kt * 2 + h] =
              ldsr(dbuf, SWZ(row, row * 384 + kt * 64 + h * 32 + hib));
        }
    acc2[0] = fz16; acc2[1] = fz16;
    VMW(10);
    __builtin_amdgcn_s_setprio(1);
#pragma unroll
    for (int rg = 0; rg < 2; ++rg) {
      acc2[rg] = mfma32(af[rg * 4 + 0], bc8(eb[0]), acc2[rg]);
      acc2[rg] = mfma32(af[rg * 4 + 1], bc8(eb[1]), acc2[rg]);
    }
    __builtin_amdgcn_s_setprio(0);
    VMW(8);
    __builtin_amdgcn_s_setprio(1);
#pragma unroll
    for (int rg = 0; rg < 2; ++rg) {
      acc2[rg] = mfma32(af[rg * 4 + 2], bc8(eb[2]), acc2[rg]);
      acc2[rg] = mfma32(af[rg * 4 + 3], bc8(eb[3]), acc2[rg]);
    }
    __builtin_amdgcn_s_setprio(0);
    // epi a1 -> hbuf cols 0 + w*32
#pragma unroll
    for (int rg = 0; rg < 2; ++rg)
#pragma unroll
      for (int r = 0; r < 16; ++r) {
        float v = acc2[rg][r] + abv;
        v = v > 0.f ? v : 0.f;
        int row = rg * 32 + (r & 3) + 8 * (r >> 2) + 4 * hi;
        *(bf16*)((char*)hbuf + SWZ(row, row * 768 + (w * 32 + l31) * 2)) = (bf16)v;
      }

    // a2: same aw frags, A from pairs cols 64..127 (+128 B)
#pragma unroll
    for (int rg = 0; rg < 2; ++rg)
#pragma unroll
      for (int kt = 0; kt < 2; ++kt)
#pragma unroll
        for (int h = 0; h < 2; ++h) {
          int row = rg * 32 + l31;
          af[rg * 4 + kt * 2 + h] =
              ldsr(dbuf, SWZ(row, row * 384 + 128 + kt * 64 + h * 32 + hib));
        }
    acc2[0] = fz16; acc2[1] = fz16;
    __builtin_amdgcn_s_setprio(1);
#pragma unroll
    for (int rg = 0; rg < 2; ++rg) {
      acc2[rg] = mfma32(af[rg * 4 + 0], bc8(eb[0]), acc2[rg]);
      acc2[rg] = mfma32(af[rg * 4 + 1], bc8(eb[1]), acc2[rg]);
      acc2[rg] = mfma32(af[rg * 4 + 2], bc8(eb[2]), acc2[rg]);
      acc2[rg] = mfma32(af[rg * 4 + 3], bc8(eb[3]), acc2[rg]);
    }
    __builtin_amdgcn_s_setprio(0);
#pragma unroll
    for (int rg = 0; rg < 2; ++rg)
#pragma unroll
      for (int r = 0; r < 16; ++r) {
        float v = acc2[rg][r] + abv;
        v = v > 0.f ? v : 0.f;
        int row = rg * 32 + (r & 3) + 8 * (r >> 2) + 4 * hi;
        *(bf16*)((char*)hbuf + SWZ(row, row * 768 + (128 + w * 32 + l31) * 2)) = (bf16)v;
      }

    // be: K=32, A from pairs cols 128..159 (+256 B), B = bw
    VMW(6);
#pragma unroll
    for (int rg = 0; rg < 2; ++rg)
#pragma unroll
      for (int h = 0; h < 2; ++h) {
        int row = rg * 32 + l31;
        af[rg * 2 + h] =
            ldsr(dbuf, SWZ(row, row * 384 + 256 + h * 32 + hib));
      }
    acc2[0] = fz16; acc2[1] = fz16;
    __builtin_amdgcn_s_setprio(1);
#pragma unroll
    for (int rg = 0; rg < 2; ++rg) {
      acc2[rg] = mfma32(af[rg * 2 + 0], bc8(eb[4]), acc2[rg]);
      acc2[rg] = mfma32(af[rg * 2 + 1], bc8(eb[5]), acc2[rg]);
    }
    __builtin_amdgcn_s_setprio(0);
#pragma unroll
    for (int rg = 0; rg < 2; ++rg)
#pragma unroll
      for (int r = 0; r < 16; ++r) {
        float v = acc2[rg][r] + bbv;
        v = v > 0.f ? v : 0.f;
        int row = rg * 32 + (r & 3) + 8 * (r >> 2) + 4 * hi;
        *(bf16*)((char*)hbuf + SWZ(row, row * 768 + (256 + w * 32 + l31) * 2)) = (bf16)v;
      }
  }

  SYNCL();   // hbuf visible; 6 p1-prologue loads still in flight

#pragma unroll
  for (int t = 0; t < 4; ++t) acc3[t] = fz16;

#pragma unroll
  for (int nc = 0; nc < 4; ++nc) {
    const int gw = nc * 4 + w;
    acc2[0] = fz16; acc2[1] = fz16;

    // ---- p1: h[64,384] @ p1w cols gw*32..+32 (32x32x16) ----
    {
      bf16x8 an[2][4];   // [kt&1][rg*2+h]
#pragma unroll
      for (int q = 0; q < 2; ++q)
#pragma unroll
        for (int rg = 0; rg < 2; ++rg)
#pragma unroll
          for (int h = 0; h < 2; ++h) {
            int row = rg * 32 + l31;
            an[q][rg * 2 + h] =
                ldsr(hbuf, SWZ(row, row * 768 + q * 64 + h * 32 + hib));
          }
#pragma unroll
      for (int kt = 0; kt < 12; ++kt) {
        bf16x8 a00 = an[kt & 1][0], a01 = an[kt & 1][1];
        bf16x8 a10 = an[kt & 1][2], a11 = an[kt & 1][3];
        if (kt < 10) {
#pragma unroll
          for (int rg = 0; rg < 2; ++rg)
#pragma unroll
            for (int h = 0; h < 2; ++h) {
              int row = rg * 32 + l31;
              an[kt & 1][rg * 2 + h] = ldsr(
                  hbuf, SWZ(row, row * 768 + (kt + 2) * 64 + h * 32 + hib));
            }
        }
        if (kt < 9) {
          gload(p1r0[(kt + 3) & 3],
                wpk + WOFF_P1 + (((size_t)gw * 12 + kt + 3) * 2 + 0) * 512 + ln8);
          gload(p1r1[(kt + 3) & 3],
                wpk + WOFF_P1 + (((size_t)gw * 12 + kt + 3) * 2 + 1) * 512 + ln8);
        }
        if (kt < 9)       { VMW(6); }
        else if (kt == 9) { VMW(4); }
        else if (kt == 10){ VMW(2); }
        else              { VMW(0); }
        __builtin_amdgcn_s_setprio(1);
        bf16x8 b0 = bc8(p1r0[kt & 3]);
        bf16x8 b1 = bc8(p1r1[kt & 3]);
        acc2[0] = mfma32(a00, b0, acc2[0]);
        acc2[1] = mfma32(a10, b0, acc2[1]);
        acc2[0] = mfma32(a01, b1, acc2[0]);
        acc2[1] = mfma32(a11, b1, acc2[1]);
        __builtin_amdgcn_s_setprio(0);
      }
    }

    // issue p2 B for kt2=0,1 (8 loads) -- hidden under epi + barrier
#pragma unroll
    for (int q = 0; q < 2; ++q)
#pragma unroll
      for (int cg = 0; cg < 2; ++cg)
#pragma unroll
        for (int h = 0; h < 2; ++h)
          gload(p2r[q][cg * 2 + h],
                wpk + WOFF_P2 +
                    (((size_t)(cg ? w + 4 : w) * 16 + nc * 4 + q) * 2 + h) * 512 +
                    ln8);

    // p1 epilogue -> chunk[nc&1] (no barrier needed before: parity disjoint)
    {
      float bv = p1bv[nc];
#pragma unroll
      for (int rg = 0; rg < 2; ++rg)
#pragma unroll
        for (int r = 0; r < 16; ++r) {
          float v = acc2[rg][r] + bv;
          v = v > 0.f ? v : 0.f;
          int row = rg * 32 + (r & 3) + 8 * (r >> 2) + 4 * hi;
          *(bf16*)((char*)dbuf +
                   SWZ(row, (nc & 1) * 16384 + row * 256 + (w * 32 + l31) * 2)) =
              (bf16)v;
        }
    }
    SYNCL();                       // h2 chunk visible (lgkm only)

    // ---- p2: h2chunk[64,128] @ p2w chunk -> acc3 (32x32x16) ----
    {
      bf16x8 an2[2][4];   // [kt2&1][rg*2+h]
#pragma unroll
      for (int q = 0; q < 2; ++q)
#pragma unroll
        for (int rg = 0; rg < 2; ++rg)
#pragma unroll
          for (int h = 0; h < 2; ++h) {
            int row = rg * 32 + l31;
            an2[q][rg * 2 + h] = ldsr(
                dbuf, SWZ(row, (nc & 1) * 16384 + row * 256 + q * 64 + h * 32 + hib));
          }
#pragma unroll
      for (int kt2 = 0; kt2 < 4; ++kt2) {
        bf16x8 ac[4];
#pragma unroll
        for (int f = 0; f < 4; ++f) ac[f] = an2[kt2 & 1][f];
        if (kt2 < 2) {
#pragma unroll
          for (int rg = 0; rg < 2; ++rg)
#pragma unroll
            for (int h = 0; h < 2; ++h) {
              int row = rg * 32 + l31;
              an2[kt2 & 1][rg * 2 + h] = ldsr(
                  dbuf, SWZ(row, (nc & 1) * 16384 + row * 256 + (kt2 + 2) * 64 +
                                     h * 32 + hib));
            }
#pragma unroll
          for (int cg = 0; cg < 2; ++cg)
#pragma unroll
            for (int h = 0; h < 2; ++h)
              gload(p2r[(kt2 + 2) % 3][cg * 2 + h],
                    wpk + WOFF_P2 +
                        (((size_t)(cg ? w + 4 : w) * 16 + nc * 4 + kt2 + 2) * 2 + h) *
                            512 + ln8);
        }
        if (kt2 == 1) {
          const int gn = ((nc + 1) & 3) * 4 + w;
#pragma unroll
          for (int q = 0; q < 3; ++q) {
            gload(p1r0[q],
                  wpk + WOFF_P1 + (((size_t)gn * 12 + q) * 2 + 0) * 512 + ln8);
            gload(p1r1[q],
                  wpk + WOFF_P1 + (((size_t)gn * 12 + q) * 2 + 1) * 512 + ln8);
          }
        }
        if (kt2 == 0)      { VMW(8); }
        else if (kt2 == 1) { VMW(14); }
        else if (kt2 == 2) { VMW(10); }
        else               { VMW(6); }
        __builtin_amdgcn_s_setprio(1);
#pragma unroll
        for (int h = 0; h < 2; ++h) {
          bf16x8 b0 = bc8(p2r[kt2 % 3][0 * 2 + h]);
          bf16x8 b1 = bc8(p2r[kt2 % 3][1 * 2 + h]);
          acc3[0] = mfma32(ac[0 * 2 + h], b0, acc3[0]);   // rg0 cg0
          acc3[1] = mfma32(ac[0 * 2 + h], b1, acc3[1]);   // rg0 cg1
          acc3[2] = mfma32(ac[1 * 2 + h], b0, acc3[2]);   // rg1 cg0
          acc3[3] = mfma32(ac[1 * 2 + h], b1, acc3[3]);   // rg1 cg1
        }
        __builtin_amdgcn_s_setprio(0);
      }
    }
  }

  // ---- masked row-sums of h3 = relu(acc3 + p2b), 32x32 C/D layout ----
  const int s0 = (64 * blk) / 100;
  const int sp = (s0 + 1) * 100 - 64 * blk;

#pragma unroll
  for (int cg = 0; cg < 2; ++cg) {
    float bv = p2bv[cg];
    float tot = 0.f, cs0 = 0.f;
#pragma unroll
    for (int rg = 0; rg < 2; ++rg)
#pragma unroll
      for (int r = 0; r < 16; ++r) {
        float v = acc3[rg * 2 + cg][r] + bv;
        v = v > 0.f ? v : 0.f;
        tot += v;
        int row = rg * 32 + (r & 3) + 8 * (r >> 2) + 4 * hi;
        cs0 += (row < sp) ? v : 0.f;
      }
    float cs1 = tot - cs0;
    cs0 += __shfl_xor(cs0, 32, 64);
    cs1 += __shfl_xor(cs1, 32, 64);
    if (lane < 32) {
      int col = (cg ? w + 4 : w) * 32 + lane;
      hsum[(size_t)(2 * blk) * 256 + col]     = cs0;
      hsum[(size_t)(2 * blk + 1) * 256 + col] = cs1;
    }
  }
}

// ---------------------------------------------------------------------------
// tail_kernel: mid+head1+head2 fused. (byte-identical to v13-v16)
// ---------------------------------------------------------------------------
__global__ __launch_bounds__(512, 2) void tail_kernel(
    const bf16* __restrict__ wpk, const float* __restrict__ hsum,
    const int* __restrict__ idxp, const float* __restrict__ p3b,
    const float* __restrict__ f1b, const float* __restrict__ f2b,
    const float* __restrict__ f3w, const float* __restrict__ f3b,
    float* __restrict__ out) {
  __shared__ __align__(16) bf16 ms[16 * LSTR_MS];
  __shared__ __align__(16) bf16 hp[16 * 1032];
  __shared__ __align__(16) bf16 h2s[16 * 520];
  __shared__ __align__(16) bf16 h3s[16 * 40];

  const int tid = threadIdx.x;
  const int w = tid >> 6;          // 0..7
  const int lane = tid & 63;
  const int lm = lane & 15;
  const int lq = lane >> 4;
  const int r0 = blockIdx.x * 16;
  const floatx4 fz = {0.f, 0.f, 0.f, 0.f};

  for (int i = tid; i < 16 * 64; i += 512) {
    int row = i >> 6, c4 = i & 63;
    int seg = r0 + row;
    int b_lo = (100 * seg) >> 6;
    int b_hi = (100 * seg + 99) >> 6;
    float4 sa = {0.f, 0.f, 0.f, 0.f};
    for (int b = b_lo; b <= b_hi; ++b) {
      int slot = (64 * b >= 100 * seg) ? 0 : 1;
      float4 v = *(const float4*)(hsum + (size_t)(2 * b + slot) * 256 + c4 * 4);
      sa.x += v.x; sa.y += v.y; sa.z += v.z; sa.w += v.w;
    }
    float inv = 1.f / (float)idxp[seg];
    bf16x4 o = {(bf16)(sa.x * inv), (bf16)(sa.y * inv),
                (bf16)(sa.z * inv), (bf16)(sa.w * inv)};
    *(bf16x4*)(ms + row * LSTR_MS + c4 * 4) = o;
  }
  __syncthreads();

#pragma unroll
  for (int nt2 = 0; nt2 < 4; ++nt2) {
    floatx4 a2[2];
    a2[0] = fz; a2[1] = fz;
#pragma unroll
    for (int kt = 0; kt < 8; ++kt) {
      bf16x8 a = *(const bf16x8*)(ms + lm * LSTR_MS + kt * 32 + lq * 8);
#pragma unroll
      for (int j = 0; j < 2; ++j) {
        bf16x8 b = *(const bf16x8*)(wpk + WOFF_P3 +
            ((size_t)((w * 8 + kt) * 128 + (nt2 * 2 + j) * 16 + lm)) * 32 +
            lq * 8);
        a2[j] = mfma16(a, b, a2[j]);
      }
    }
#pragma unroll
    for (int j = 0; j < 2; ++j) {
      int col = w * 128 + (nt2 * 2 + j) * 16 + lm;
      float bv = p3b[col];
#pragma unroll
      for (int r = 0; r < 4; ++r)
        hp[(lq * 4 + r) * 1032 + col] = (bf16)(a2[j][r] + bv);
    }
  }
  __syncthreads();

  {
    floatx4 a4[4];
#pragma unroll
    for (int j = 0; j < 4; ++j) a4[j] = fz;
#pragma unroll 8
    for (int kt = 0; kt < 32; ++kt) {
      bf16x8 a = *(const bf16x8*)(hp + lm * 1032 + kt * 32 + lq * 8);
#pragma unroll
      for (int j = 0; j < 4; ++j) {
        bf16x8 b = *(const bf16x8*)(wpk + WOFF_F1 +
            ((size_t)(((w >> 1) * 32 + kt) * 128 + (w & 1) * 64 + j * 16 + lm)) * 32 +
            lq * 8);
        a4[j] = mfma16(a, b, a4[j]);
      }
    }
#pragma unroll
    for (int j = 0; j < 4; ++j) {
      int col = w * 64 + j * 16 + lm;
      float bv = f1b[col];
#pragma unroll
      for (int r = 0; r < 4; ++r) {
        float v = a4[j][r] + bv;
        v = v > 0.f ? v : 0.f;
        h2s[(lq * 4 + r) * 520 + col] = (bf16)v;
      }
    }
  }
  __syncthreads();

  if (w < 2) {
    floatx4 c2 = fz;
#pragma unroll
    for (int kt = 0; kt < 16; ++kt) {
      bf16x8 a = *(const bf16x8*)(h2s + lm * 520 + kt * 32 + lq * 8);
      bf16x8 b = *(const bf16x8*)(wpk + WOFF_F2 +
                    ((size_t)(kt * 32 + w * 16 + lm)) * 32 + lq * 8);
      c2 = mfma16(a, b, c2);
    }
    int col = w * 16 + lm;
    float bv = f2b[col];
#pragma unroll
    for (int r = 0; r < 4; ++r) {
      float v = c2[r] + bv;
      v = v > 0.f ? v : 0.f;
      h3s[(lq * 4 + r) * 40 + col] = (bf16)v;
    }
  }
  __syncthreads();
  if (w == 0) {
    float ps = 0.f;
#pragma unroll
    for (int jj = 0; jj < 8; ++jj)
      ps += (float)h3s[lm * 40 + lq * 8 + jj] * f3w[lq * 8 + jj];
    ps += __shfl_xor(ps, 16, 64);
    ps += __shfl_xor(ps, 32, 64);
    if (lq == 0) out[r0 + lm] = ps + f3b[0];
  }
}

// ---------------------------------------------------------------------------
extern "C" void kernel_launch(void* const* d_in, const int* in_sizes, int n_in,
                              void* d_out, int out_size, void* d_ws,
                              size_t ws_size, hipStream_t stream) {
  (void)in_sizes; (void)n_in; (void)out_size; (void)ws_size;
  const float* pairs = (const float*)d_in[0];
  const int*   idxp  = (const int*)d_in[1];
  // d_in[2] = ref_feats (unused by the reference)
  const float* aw  = (const float*)d_in[3];
  const float* ab  = (const float*)d_in[4];
  const float* bw  = (const float*)d_in[5];
  const float* bb  = (const float*)d_in[6];
  const float* p1w = (const float*)d_in[7];
  const float* p1b = (const float*)d_in[8];
  const float* p2w = (const float*)d_in[9];
  const float* p2b = (const float*)d_in[10];
  const float* p3w = (const float*)d_in[11];
  const float* p3b = (const float*)d_in[12];
  const float* f1w = (const float*)d_in[13];
  const float* f1b = (const float*)d_in[14];
  const float* f2w = (const float*)d_in[15];
  const float* f2b = (const float*)d_in[16];
  const float* f3w = (const float*)d_in[17];
  const float* f3b = (const float*)d_in[18];

  bf16* wpk = (bf16*)d_ws;
  float* hsum = (float*)(wpk + WOFF_HS);

  pack_lds<<<566, 256, 0, stream>>>(aw, bw, p1w, p2w, p3w, f1w, f2w, wpk);
  seg_kernel<<<NWIN, 256, 0, stream>>>(pairs, ab, bb, p1b, p2b, wpk, hsum);
  tail_kernel<<<125, 512, 0, stream>>>(wpk, hsum, idxp, p3b, f1b, f2b, f3w,
                                       f3b, (float*)d_out);
}

// Round 11
// 510.448 us; speedup vs baseline: 1.3365x; 1.3365x over previous
//
#include <hip/hip_runtime.h>
#include <cstdint>
#include <cstddef>

// ---------------------------------------------------------------------------
// TGNN fused pipeline v18 = v16 + single-barrier-per-nc chunk double-buffer,
// with LDS in FRAGMENT-PACKED layout instead of v17's XOR swizzle.
// v17 postmortem: seg 490us REGRESSION = scratch spill (WRITE_SIZE 521MB,
// FETCH 370MB) from embed's asm conversion (eb[6]+af[8]+prologue all
// asm-pinned VGPRs concurrently); swizzle also regressed bank conflicts
// (1.1e6 -> 1.39e7). absmax=0 proved swizzle math AND single-barrier parity
// both correct -- only pressure/banking were wrong.
// v18: embed reverted to v16's exact 16x16 compiler path (aw/bw old packing);
// h/h2 stored frag-packed: slot(k,row) = ((k>>3)*64+row)*8+(k&7). Every hot
// b128 read = base + ko*1024 + row*16 -> 64 lanes x 16B sequential = uniform
// banks, zero pad. hbuf 49152 + 2 chunks 32768 = 81920 B = EXACTLY 2
// blocks/CU. Pairs stage frag-packed in chunk region (consumed pre-chunk0,
// barrier-ordered). v16's verified VMW schedule verbatim. Barriers 10 -> 6.
// Tripwires: WRITE_SIZE exactly 6250KB (spill); VGPR ~112-120; absmax 0;
// Occupancy ~20 (if ~10 LDS didn't fit).
// ---------------------------------------------------------------------------

typedef __bf16 bf16;
typedef __attribute__((ext_vector_type(8))) __bf16 bf16x8;
typedef __attribute__((ext_vector_type(4))) __bf16 bf16x4;
typedef __attribute__((ext_vector_type(4))) float floatx4;
typedef __attribute__((ext_vector_type(16))) float floatx16;

#define GRP 100
#define NWIN 3125        // 200000 rows / 64

// packed-ws element offsets (bf16 elements)
#define WOFF_AW 0
#define WOFF_BW 8192
#define WOFF_P1 12288
#define WOFF_P2 208896
#define WOFF_P3 339968
#define WOFF_F1 602112
#define WOFF_F2 1126400
#define WOFF_HS 1142784          // hsum [6250][256] f32 (2 bf16 elems each)

#define LSTR_MS 264

static __device__ __forceinline__ floatx4 mfma16(bf16x8 a, bf16x8 b, floatx4 c) {
  return __builtin_amdgcn_mfma_f32_16x16x32_bf16(a, b, c, 0, 0, 0);
}
static __device__ __forceinline__ floatx16 mfma32(bf16x8 a, bf16x8 b, floatx16 c) {
  return __builtin_amdgcn_mfma_f32_32x32x16_bf16(a, b, c, 0, 0, 0);
}

static __device__ __forceinline__ void gload(floatx4& d, const bf16* p) {
  asm volatile("global_load_dwordx4 %0, %1, off" : "=v"(d) : "v"(p));
}
static __device__ __forceinline__ bf16x8 bc8(floatx4 v) {
  return __builtin_bit_cast(bf16x8, v);
}

#define VMW(N)                                         \
  do {                                                 \
    asm volatile("s_waitcnt vmcnt(" #N ")");           \
    __builtin_amdgcn_sched_barrier(0);                 \
  } while (0)

#define SYNCL()                                        \
  do {                                                 \
    asm volatile("s_waitcnt lgkmcnt(0)" ::: "memory"); \
    __builtin_amdgcn_s_barrier();                      \
  } while (0)

// ---------------------------------------------------------------------------
// Coalesced weight repack (v16 verbatim): newf layout for p1w/p2w (1KB chunk
// per (g,kt,h)); old CW=128 layout for aw/bw/p3w/f1w/f2w.
// ---------------------------------------------------------------------------
__global__ __launch_bounds__(256) void pack_lds(
    const float* __restrict__ aw, const float* __restrict__ bw,
    const float* __restrict__ p1w, const float* __restrict__ p2w,
    const float* __restrict__ p3w, const float* __restrict__ f1w,
    const float* __restrict__ f2w, bf16* __restrict__ wpk) {
  __shared__ float t[32][65];
  const int tid = threadIdx.x;
  int b = blockIdx.x;

  if (b < 550) {
    const float* src; int dstoff, K, N, tt;
    bool newf = false;
    if (b < 4)        { src = aw;  dstoff = WOFF_AW; K = 64;   N = 128;  tt = b; }
    else if (b < 6)   { src = bw;  dstoff = WOFF_BW; K = 32;   N = 128;  tt = b - 4; }
    else if (b < 102) { src = p1w; dstoff = WOFF_P1; K = 384;  N = 512;  tt = b - 6;   newf = true; }
    else if (b < 166) { src = p2w; dstoff = WOFF_P2; K = 512;  N = 256;  tt = b - 102; newf = true; }
    else if (b < 294) { src = p3w; dstoff = WOFF_P3; K = 256;  N = 1024; tt = b - 166; }
    else              { src = f1w; dstoff = WOFF_F1; K = 1024; N = 512;  tt = b - 294; }
    const int KT = K >> 5;
    const int kt = tt % KT;
    const int n0 = (tt / KT) * 64;
    for (int i = tid; i < 2048; i += 256) {
      int r = i >> 6, c = i & 63;
      t[r][c] = src[(size_t)(kt * 32 + r) * N + n0 + c];
    }
    __syncthreads();
    if (newf) {
      const int cpp = tid & 63, rb = tid >> 6;      // col-in-64, k-oct
      const int g = (n0 >> 5) + (cpp >> 5);
      const int c = cpp & 31;
      bf16x8 v;
#pragma unroll
      for (int i = 0; i < 8; ++i) v[i] = (bf16)t[rb * 8 + i][cpp];
      *(bf16x8*)(wpk + dstoff +
                 (((size_t)g * KT + kt) * 2 + (rb >> 1)) * 512 +
                 (c + 32 * (rb & 1)) * 8) = v;
    } else {
      const int nc = n0 >> 7, nl0 = n0 & 127;
      bf16* dst = wpk + dstoff + ((size_t)(nc * KT + kt) * 128 + nl0) * 32;
      int o = tid * 8;
      int nl = o >> 5, kk = o & 31;
      bf16x8 v;
#pragma unroll
      for (int i = 0; i < 8; ++i) v[i] = (bf16)t[kk + i][nl];
      *(bf16x8*)(dst + nl * 32 + kk) = v;
    }
  } else {
    const int kt = b - 550;
    for (int i = tid; i < 1024; i += 256) {
      int r = i >> 5, c = i & 31;
      t[r][c] = f2w[(size_t)(kt * 32 + r) * 32 + c];
    }
    __syncthreads();
    if (tid < 128) {
      int o = tid * 8;
      int nl = o >> 5, kk = o & 31;
      bf16x8 v;
#pragma unroll
      for (int i = 0; i < 8; ++i) v[i] = (bf16)t[kk + i][nl];
      *(bf16x8*)(wpk + WOFF_F2 + kt * 1024 + nl * 32 + kk) = v;
    }
  }
}

// embed kstep: A from frag-packed LDS, B from global old-layout (16x16)
static __device__ __forceinline__ void ks2f(const bf16* __restrict__ db, int acol,
                                            const bf16* __restrict__ b0p,
                                            const bf16* __restrict__ b1p,
                                            floatx4* acc, int lm, int lq) {
  bf16x8 b0 = *(const bf16x8*)b0p;
  bf16x8 b1 = *(const bf16x8*)b1p;
  const int ko = (acol >> 3) + lq;          // k-oct index
#pragma unroll
  for (int mt = 0; mt < 4; ++mt) {
    int row = mt * 16 + lm;
    bf16x8 a = *(const bf16x8*)(db + (ko * 64 + row) * 8);
    acc[mt * 2]     = mfma16(a, b0, acc[mt * 2]);
    acc[mt * 2 + 1] = mfma16(a, b1, acc[mt * 2 + 1]);
  }
}

// embed epilogue: relu(acc+bias) -> frag-packed hbuf (16x16 C/D layout)
static __device__ __forceinline__ void epi2f(const floatx4* acc,
                                             const float* __restrict__ bias,
                                             bf16* __restrict__ hb, int colbase,
                                             int w, int lm, int lq) {
#pragma unroll
  for (int mt = 0; mt < 4; ++mt)
#pragma unroll
    for (int j = 0; j < 2; ++j) {
      int c = (w + 4 * j) * 16 + lm;
      float bv = bias[c];
      floatx4 cc = acc[mt * 2 + j];
      int k = colbase + c;
      int base = (k >> 3) * 512 + (k & 7);
#pragma unroll
      for (int r = 0; r < 4; ++r) {
        float v = cc[r] + bv;
        v = v > 0.f ? v : 0.f;
        int row = mt * 16 + lq * 4 + r;
        hb[base + row * 8] = (bf16)v;
      }
    }
}

// ---------------------------------------------------------------------------
// seg_kernel: one block per 64-row WINDOW. Embed 16x16 (compiler path, v16);
// p1/p2 32x32x16 with v16's asm B-pipeline. LDS frag-packed:
// hbuf 49152 B (h[64,384]); dbuf 32768 B = pairs (frag, K=160) then 2x h2
// chunks (frag, K=128, 8192 elems each). 6 barriers/block.
// ---------------------------------------------------------------------------
__global__ __launch_bounds__(256, 2) void seg_kernel(
    const float* __restrict__ pairs, const float* __restrict__ ab,
    const float* __restrict__ bb, const float* __restrict__ p1b,
    const float* __restrict__ p2b, const bf16* __restrict__ wpk,
    float* __restrict__ hsum) {
  __shared__ __align__(16) bf16 hbuf[64 * 384];
  __shared__ __align__(16) bf16 dbuf[2 * 64 * 128];

  const int tid = threadIdx.x;
  const int w = tid >> 6;
  const int lane = tid & 63;
  const int lm = lane & 15;
  const int lq = lane >> 4;
  const int l31 = lane & 31;
  const int hi = lane >> 5;
  const int ln8 = lane * 8;       // elems
  const int blk = blockIdx.x;

  // ---- stage pairs [64,160] fp32 -> frag-packed bf16 in dbuf ----
  {
    const float4* src = (const float4*)(pairs + (size_t)blk * (64 * 160));
    for (int i = tid; i < 64 * 40; i += 256) {
      int row = i / 40;
      int c4 = i - row * 40;               // group of 4 elems, k0 = c4*4
      float4 v = src[i];
      bf16x4 o = {(bf16)v.x, (bf16)v.y, (bf16)v.z, (bf16)v.w};
      *(bf16x4*)(dbuf + ((c4 >> 1) * 64 + row) * 8 + (c4 & 1) * 4) = o;
    }
  }
  SYNCL();

  const floatx4 fz = {0.f, 0.f, 0.f, 0.f};
  const floatx16 fz16 = {0.f, 0.f, 0.f, 0.f, 0.f, 0.f, 0.f, 0.f,
                         0.f, 0.f, 0.f, 0.f, 0.f, 0.f, 0.f, 0.f};
  floatx4 acc[8];

  // ---------------- embed: a1 / a2 / be -> frag-packed hbuf ----------------
#pragma unroll
  for (int t = 0; t < 8; ++t) acc[t] = fz;
#pragma unroll
  for (int kt = 0; kt < 2; ++kt)
    ks2f(dbuf, kt * 32,
         wpk + WOFF_AW + ((size_t)(kt * 128 + w * 16 + lm)) * 32 + lq * 8,
         wpk + WOFF_AW + ((size_t)(kt * 128 + (w + 4) * 16 + lm)) * 32 + lq * 8,
         acc, lm, lq);
  epi2f(acc, ab, hbuf, 0, w, lm, lq);
#pragma unroll
  for (int t = 0; t < 8; ++t) acc[t] = fz;
#pragma unroll
  for (int kt = 0; kt < 2; ++kt)
    ks2f(dbuf, 64 + kt * 32,
         wpk + WOFF_AW + ((size_t)(kt * 128 + w * 16 + lm)) * 32 + lq * 8,
         wpk + WOFF_AW + ((size_t)(kt * 128 + (w + 4) * 16 + lm)) * 32 + lq * 8,
         acc, lm, lq);
  epi2f(acc, ab, hbuf, 128, w, lm, lq);
#pragma unroll
  for (int t = 0; t < 8; ++t) acc[t] = fz;
  ks2f(dbuf, 128,
       wpk + WOFF_BW + ((size_t)(w * 16 + lm)) * 32 + lq * 8,
       wpk + WOFF_BW + ((size_t)((w + 4) * 16 + lm)) * 32 + lq * 8,
       acc, lm, lq);
  epi2f(acc, bb, hbuf, 256, w, lm, lq);

  // ---- preload p1/p2 biases into registers (no vmem inside asm phases) ----
  float p1bv[4], p2bv[2];
#pragma unroll
  for (int nc = 0; nc < 4; ++nc) p1bv[nc] = p1b[nc * 128 + w * 32 + l31];
  p2bv[0] = p2b[w * 32 + l31];
  p2bv[1] = p2b[(w + 4) * 32 + l31];
  asm volatile("" : "+v"(p1bv[0]), "+v"(p1bv[1]), "+v"(p1bv[2]),
                    "+v"(p1bv[3]), "+v"(p2bv[0]), "+v"(p2bv[1]));

  floatx4 p1r0[4], p1r1[4];   // p1 B slots (4-slot, 3-kt lead)
  floatx4 p2r[3][4];          // p2 B slots (3-slot)
  floatx16 acc2[2];
  floatx16 acc3[4];

  // prologue: nc=0 p1 chunks kt=0..2 (6 loads) -- in flight across SYNCL
#pragma unroll
  for (int q = 0; q < 3; ++q) {
    gload(p1r0[q], wpk + WOFF_P1 + (((size_t)w * 12 + q) * 2 + 0) * 512 + ln8);
    gload(p1r1[q], wpk + WOFF_P1 + (((size_t)w * 12 + q) * 2 + 1) * 512 + ln8);
  }
  SYNCL();   // hbuf visible; p1 B loads stay in flight

#pragma unroll
  for (int t = 0; t < 4; ++t) acc3[t] = fz16;

  // chunk k-index components for the p1 epilogue (k = w*32 + l31)
  const int ckb = ((w * 32 + l31) >> 3) * 512 + ((w * 32 + l31) & 7);

#pragma unroll
  for (int nc = 0; nc < 4; ++nc) {
    const int gw = nc * 4 + w;
    bf16* ch = dbuf + (nc & 1) * 8192;
    acc2[0] = fz16; acc2[1] = fz16;

    // ---- p1: h[64,384] @ p1w cols gw*32..+32 (32x32x16) ----
    {
      bf16x8 an[2][4];   // [kt&1][rg*2+h]
#pragma unroll
      for (int q = 0; q < 2; ++q)
#pragma unroll
        for (int rg = 0; rg < 2; ++rg)
#pragma unroll
          for (int h = 0; h < 2; ++h)
            an[q][rg * 2 + h] = *(const bf16x8*)(
                hbuf + ((q * 4 + h * 2 + hi) * 64 + rg * 32 + l31) * 8);
#pragma unroll
      for (int kt = 0; kt < 12; ++kt) {
        bf16x8 a00 = an[kt & 1][0], a01 = an[kt & 1][1];
        bf16x8 a10 = an[kt & 1][2], a11 = an[kt & 1][3];
        if (kt < 10) {
#pragma unroll
          for (int rg = 0; rg < 2; ++rg)
#pragma unroll
            for (int h = 0; h < 2; ++h)
              an[kt & 1][rg * 2 + h] = *(const bf16x8*)(
                  hbuf + (((kt + 2) * 4 + h * 2 + hi) * 64 + rg * 32 + l31) * 8);
        }
        if (kt < 9) {
          gload(p1r0[(kt + 3) & 3],
                wpk + WOFF_P1 + (((size_t)gw * 12 + kt + 3) * 2 + 0) * 512 + ln8);
          gload(p1r1[(kt + 3) & 3],
                wpk + WOFF_P1 + (((size_t)gw * 12 + kt + 3) * 2 + 1) * 512 + ln8);
        }
        if (kt < 9)       { VMW(6); }
        else if (kt == 9) { VMW(4); }
        else if (kt == 10){ VMW(2); }
        else              { VMW(0); }
        __builtin_amdgcn_s_setprio(1);
        bf16x8 b0 = bc8(p1r0[kt & 3]);
        bf16x8 b1 = bc8(p1r1[kt & 3]);
        acc2[0] = mfma32(a00, b0, acc2[0]);
        acc2[1] = mfma32(a10, b0, acc2[1]);
        acc2[0] = mfma32(a01, b1, acc2[0]);
        acc2[1] = mfma32(a11, b1, acc2[1]);
        __builtin_amdgcn_s_setprio(0);
      }
    }

    // issue p2 B for kt2=0,1 (8 loads) -- hidden under epi + barrier
#pragma unroll
    for (int q = 0; q < 2; ++q)
#pragma unroll
      for (int cg = 0; cg < 2; ++cg)
#pragma unroll
        for (int h = 0; h < 2; ++h)
          gload(p2r[q][cg * 2 + h],
                wpk + WOFF_P2 +
                    (((size_t)(cg ? w + 4 : w) * 16 + nc * 4 + q) * 2 + h) * 512 +
                    ln8);

    // p1 epilogue -> chunk[nc&1] frag-packed (no barrier before: parity)
    {
      float bv = p1bv[nc];
#pragma unroll
      for (int rg = 0; rg < 2; ++rg)
#pragma unroll
        for (int r = 0; r < 16; ++r) {
          float v = acc2[rg][r] + bv;
          v = v > 0.f ? v : 0.f;
          int row = rg * 32 + (r & 3) + 8 * (r >> 2) + 4 * hi;
          ch[ckb + row * 8] = (bf16)v;
        }
    }
    SYNCL();                       // h2 chunk visible (lgkm only)

    // ---- p2: h2chunk[64,128] @ p2w chunk -> acc3 (32x32x16) ----
    {
      bf16x8 an2[2][4];   // [kt2&1][rg*2+h]
#pragma unroll
      for (int q = 0; q < 2; ++q)
#pragma unroll
        for (int rg = 0; rg < 2; ++rg)
#pragma unroll
          for (int h = 0; h < 2; ++h)
            an2[q][rg * 2 + h] = *(const bf16x8*)(
                ch + ((q * 4 + h * 2 + hi) * 64 + rg * 32 + l31) * 8);
#pragma unroll
      for (int kt2 = 0; kt2 < 4; ++kt2) {
        bf16x8 ac[4];
#pragma unroll
        for (int f = 0; f < 4; ++f) ac[f] = an2[kt2 & 1][f];
        if (kt2 < 2) {
#pragma unroll
          for (int rg = 0; rg < 2; ++rg)
#pragma unroll
            for (int h = 0; h < 2; ++h)
              an2[kt2 & 1][rg * 2 + h] = *(const bf16x8*)(
                  ch + (((kt2 + 2) * 4 + h * 2 + hi) * 64 + rg * 32 + l31) * 8);
#pragma unroll
          for (int cg = 0; cg < 2; ++cg)
#pragma unroll
            for (int h = 0; h < 2; ++h)
              gload(p2r[(kt2 + 2) % 3][cg * 2 + h],
                    wpk + WOFF_P2 +
                        (((size_t)(cg ? w + 4 : w) * 16 + nc * 4 + kt2 + 2) * 2 + h) *
                            512 + ln8);
        }
        if (kt2 == 1) {
          const int gn = ((nc + 1) & 3) * 4 + w;
#pragma unroll
          for (int q = 0; q < 3; ++q) {
            gload(p1r0[q],
                  wpk + WOFF_P1 + (((size_t)gn * 12 + q) * 2 + 0) * 512 + ln8);
            gload(p1r1[q],
                  wpk + WOFF_P1 + (((size_t)gn * 12 + q) * 2 + 1) * 512 + ln8);
          }
        }
        if (kt2 == 0)      { VMW(8); }
        else if (kt2 == 1) { VMW(14); }
        else if (kt2 == 2) { VMW(10); }
        else               { VMW(6); }
        __builtin_amdgcn_s_setprio(1);
#pragma unroll
        for (int h = 0; h < 2; ++h) {
          bf16x8 b0 = bc8(p2r[kt2 % 3][0 * 2 + h]);
          bf16x8 b1 = bc8(p2r[kt2 % 3][1 * 2 + h]);
          acc3[0] = mfma32(ac[0 * 2 + h], b0, acc3[0]);   // rg0 cg0
          acc3[1] = mfma32(ac[0 * 2 + h], b1, acc3[1]);   // rg0 cg1
          acc3[2] = mfma32(ac[1 * 2 + h], b0, acc3[2]);   // rg1 cg0
          acc3[3] = mfma32(ac[1 * 2 + h], b1, acc3[3]);   // rg1 cg1
        }
        __builtin_amdgcn_s_setprio(0);
      }
    }
  }

  // ---- masked row-sums of h3 = relu(acc3 + p2b), 32x32 C/D layout ----
  const int s0 = (64 * blk) / 100;
  const int sp = (s0 + 1) * 100 - 64 * blk;

#pragma unroll
  for (int cg = 0; cg < 2; ++cg) {
    float bv = p2bv[cg];
    float tot = 0.f, cs0 = 0.f;
#pragma unroll
    for (int rg = 0; rg < 2; ++rg)
#pragma unroll
      for (int r = 0; r < 16; ++r) {
        float v = acc3[rg * 2 + cg][r] + bv;
        v = v > 0.f ? v : 0.f;
        tot += v;
        int row = rg * 32 + (r & 3) + 8 * (r >> 2) + 4 * hi;
        cs0 += (row < sp) ? v : 0.f;
      }
    float cs1 = tot - cs0;
    cs0 += __shfl_xor(cs0, 32, 64);
    cs1 += __shfl_xor(cs1, 32, 64);
    if (lane < 32) {
      int col = (cg ? w + 4 : w) * 32 + lane;
      hsum[(size_t)(2 * blk) * 256 + col]     = cs0;
      hsum[(size_t)(2 * blk + 1) * 256 + col] = cs1;
    }
  }
}

// ---------------------------------------------------------------------------
// tail_kernel: mid+head1+head2 fused. (byte-identical to v13-v17)
// ---------------------------------------------------------------------------
__global__ __launch_bounds__(512, 2) void tail_kernel(
    const bf16* __restrict__ wpk, const float* __restrict__ hsum,
    const int* __restrict__ idxp, const float* __restrict__ p3b,
    const float* __restrict__ f1b, const float* __restrict__ f2b,
    const float* __restrict__ f3w, const float* __restrict__ f3b,
    float* __restrict__ out) {
  __shared__ __align__(16) bf16 ms[16 * LSTR_MS];
  __shared__ __align__(16) bf16 hp[16 * 1032];
  __shared__ __align__(16) bf16 h2s[16 * 520];
  __shared__ __align__(16) bf16 h3s[16 * 40];

  const int tid = threadIdx.x;
  const int w = tid >> 6;          // 0..7
  const int lane = tid & 63;
  const int lm = lane & 15;
  const int lq = lane >> 4;
  const int r0 = blockIdx.x * 16;
  const floatx4 fz = {0.f, 0.f, 0.f, 0.f};

  for (int i = tid; i < 16 * 64; i += 512) {
    int row = i >> 6, c4 = i & 63;
    int seg = r0 + row;
    int b_lo = (100 * seg) >> 6;
    int b_hi = (100 * seg + 99) >> 6;
    float4 sa = {0.f, 0.f, 0.f, 0.f};
    for (int b = b_lo; b <= b_hi; ++b) {
      int slot = (64 * b >= 100 * seg) ? 0 : 1;
      float4 v = *(const float4*)(hsum + (size_t)(2 * b + slot) * 256 + c4 * 4);
      sa.x += v.x; sa.y += v.y; sa.z += v.z; sa.w += v.w;
    }
    float inv = 1.f / (float)idxp[seg];
    bf16x4 o = {(bf16)(sa.x * inv), (bf16)(sa.y * inv),
                (bf16)(sa.z * inv), (bf16)(sa.w * inv)};
    *(bf16x4*)(ms + row * LSTR_MS + c4 * 4) = o;
  }
  __syncthreads();

#pragma unroll
  for (int nt2 = 0; nt2 < 4; ++nt2) {
    floatx4 a2[2];
    a2[0] = fz; a2[1] = fz;
#pragma unroll
    for (int kt = 0; kt < 8; ++kt) {
      bf16x8 a = *(const bf16x8*)(ms + lm * LSTR_MS + kt * 32 + lq * 8);
#pragma unroll
      for (int j = 0; j < 2; ++j) {
        bf16x8 b = *(const bf16x8*)(wpk + WOFF_P3 +
            ((size_t)((w * 8 + kt) * 128 + (nt2 * 2 + j) * 16 + lm)) * 32 +
            lq * 8);
        a2[j] = mfma16(a, b, a2[j]);
      }
    }
#pragma unroll
    for (int j = 0; j < 2; ++j) {
      int col = w * 128 + (nt2 * 2 + j) * 16 + lm;
      float bv = p3b[col];
#pragma unroll
      for (int r = 0; r < 4; ++r)
        hp[(lq * 4 + r) * 1032 + col] = (bf16)(a2[j][r] + bv);
    }
  }
  __syncthreads();

  {
    floatx4 a4[4];
#pragma unroll
    for (int j = 0; j < 4; ++j) a4[j] = fz;
#pragma unroll 8
    for (int kt = 0; kt < 32; ++kt) {
      bf16x8 a = *(const bf16x8*)(hp + lm * 1032 + kt * 32 + lq * 8);
#pragma unroll
      for (int j = 0; j < 4; ++j) {
        bf16x8 b = *(const bf16x8*)(wpk + WOFF_F1 +
            ((size_t)(((w >> 1) * 32 + kt) * 128 + (w & 1) * 64 + j * 16 + lm)) * 32 +
            lq * 8);
        a4[j] = mfma16(a, b, a4[j]);
      }
    }
#pragma unroll
    for (int j = 0; j < 4; ++j) {
      int col = w * 64 + j * 16 + lm;
      float bv = f1b[col];
#pragma unroll
      for (int r = 0; r < 4; ++r) {
        float v = a4[j][r] + bv;
        v = v > 0.f ? v : 0.f;
        h2s[(lq * 4 + r) * 520 + col] = (bf16)v;
      }
    }
  }
  __syncthreads();

  if (w < 2) {
    floatx4 c2 = fz;
#pragma unroll
    for (int kt = 0; kt < 16; ++kt) {
      bf16x8 a = *(const bf16x8*)(h2s + lm * 520 + kt * 32 + lq * 8);
      bf16x8 b = *(const bf16x8*)(wpk + WOFF_F2 +
                    ((size_t)(kt * 32 + w * 16 + lm)) * 32 + lq * 8);
      c2 = mfma16(a, b, c2);
    }
    int col = w * 16 + lm;
    float bv = f2b[col];
#pragma unroll
    for (int r = 0; r < 4; ++r) {
      float v = c2[r] + bv;
      v = v > 0.f ? v : 0.f;
      h3s[(lq * 4 + r) * 40 + col] = (bf16)v;
    }
  }
  __syncthreads();
  if (w == 0) {
    float ps = 0.f;
#pragma unroll
    for (int jj = 0; jj < 8; ++jj)
      ps += (float)h3s[lm * 40 + lq * 8 + jj] * f3w[lq * 8 + jj];
    ps += __shfl_xor(ps, 16, 64);
    ps += __shfl_xor(ps, 32, 64);
    if (lq == 0) out[r0 + lm] = ps + f3b[0];
  }
}

// ---------------------------------------------------------------------------
extern "C" void kernel_launch(void* const* d_in, const int* in_sizes, int n_in,
                              void* d_out, int out_size, void* d_ws,
                              size_t ws_size, hipStream_t stream) {
  (void)in_sizes; (void)n_in; (void)out_size; (void)ws_size;
  const float* pairs = (const float*)d_in[0];
  const int*   idxp  = (const int*)d_in[1];
  // d_in[2] = ref_feats (unused by the reference)
  const float* aw  = (const float*)d_in[3];
  const float* ab  = (const float*)d_in[4];
  const float* bw  = (const float*)d_in[5];
  const float* bb  = (const float*)d_in[6];
  const float* p1w = (const float*)d_in[7];
  const float* p1b = (const float*)d_in[8];
  const float* p2w = (const float*)d_in[9];
  const float* p2b = (const float*)d_in[10];
  const float* p3w = (const float*)d_in[11];
  const float* p3b = (const float*)d_in[12];
  const float* f1w = (const float*)d_in[13];
  const float* f1b = (const float*)d_in[14];
  const float* f2w = (const float*)d_in[15];
  const float* f2b = (const float*)d_in[16];
  const float* f3w = (const float*)d_in[17];
  const float* f3b = (const float*)d_in[18];

  bf16* wpk = (bf16*)d_ws;
  float* hsum = (float*)(wpk + WOFF_HS);

  pack_lds<<<566, 256, 0, stream>>>(aw, bw, p1w, p2w, p3w, f1w, f2w, wpk);
  seg_kernel<<<NWIN, 256, 0, stream>>>(pairs, ab, bb, p1b, p2b, wpk, hsum);
  tail_kernel<<<125, 512, 0, stream>>>(wpk, hsum, idxp, p3b, f1b, f2b, f3w,
                                       f3b, (float*)d_out);
}

// Round 12
// 384.977 us; speedup vs baseline: 1.7720x; 1.3259x over previous
//
#include <hip/hip_runtime.h>
#include <cstdint>
#include <cstddef>

// ---------------------------------------------------------------------------
// TGNN fused pipeline v19 = EXACT REVERT to v16 (best verified: 387us total,
// seg 194.4us, MfmaUtil 31.8, zero spill).
// v17/v18 postmortem (both regressions): the single-barrier-per-nc scheme is
// CORRECT (absmax 0 twice) but needs arch registers that don't exist -- v16
// sits at 112 arch + ~128 acc = 240 of the 256 unified-RF cap (2 waves/SIMD).
// v17's asm embed (+eb/af regs) and v18's frag-packed addressing (+~16 arch)
// each crossed 256 -> ~81KB/block scratch cascade (WRITE_SIZE 521/253 MB).
// Lesson: at this tile config there are <=16 spare regs; barrier reduction
// is blocked without a full re-tile (8-wave/256-row = new template, risky).
// v16 recap: sliding 64-row windows (no padding), p3 eliminated algebraically
// (segsum commutes with GEMM), embed 16x16 compiler path, p1/p2 32x32x16
// MFMA with inline-asm gload + counted vmcnt pipeline (4-slot p1 waits
// 6/4/2/0; 3-slot p2 waits 8/14/10/6; prologue hoisted), masked straddle
// row-sums from registers, fused tail.
// Tripwires (must reproduce round 9): seg 194+-1us, VGPR 112, WRITE_SIZE
// exactly 6250KB, bank-conflict ~1.1e6, absmax 0.
// ---------------------------------------------------------------------------

typedef __bf16 bf16;
typedef __attribute__((ext_vector_type(8))) __bf16 bf16x8;
typedef __attribute__((ext_vector_type(4))) __bf16 bf16x4;
typedef __attribute__((ext_vector_type(4))) float floatx4;
typedef __attribute__((ext_vector_type(16))) float floatx16;

#define GRP 100
#define NWIN 3125        // 200000 rows / 64

// packed-ws element offsets (bf16 elements)
#define WOFF_AW 0
#define WOFF_BW 8192
#define WOFF_P1 12288
#define WOFF_P2 208896
#define WOFF_P3 339968
#define WOFF_F1 602112
#define WOFF_F2 1126400
#define WOFF_HS 1142784          // hsum [6250][256] f32 (2 bf16 elems each)

// LDS strides (bf16 elems): %8==0 (16B-aligned b128 rows)
#define LSTR_P  168
#define LSTR_H  392
#define LSTR_H2 136
#define LSTR_MS 264

static __device__ __forceinline__ floatx4 mfma16(bf16x8 a, bf16x8 b, floatx4 c) {
  return __builtin_amdgcn_mfma_f32_16x16x32_bf16(a, b, c, 0, 0, 0);
}
static __device__ __forceinline__ floatx16 mfma32(bf16x8 a, bf16x8 b, floatx16 c) {
  return __builtin_amdgcn_mfma_f32_32x32x16_bf16(a, b, c, 0, 0, 0);
}

// async B-load: 16B global -> 4 VGPR; completion tracked ONLY by our vmcnt
static __device__ __forceinline__ void gload(floatx4& d, const bf16* p) {
  asm volatile("global_load_dwordx4 %0, %1, off" : "=v"(d) : "v"(p));
}
static __device__ __forceinline__ bf16x8 bc8(floatx4 v) {
  return __builtin_bit_cast(bf16x8, v);
}

// wait until <=N of our asm loads outstanding, then fence the scheduler so
// MFMAs can't hoist above the wait (guide rule #18)
#define VMW(N)                                         \
  do {                                                 \
    asm volatile("s_waitcnt vmcnt(" #N ")");           \
    __builtin_amdgcn_sched_barrier(0);                 \
  } while (0)

// barrier with LDS-only drain: global loads stay in flight across it
#define SYNCL()                                        \
  do {                                                 \
    asm volatile("s_waitcnt lgkmcnt(0)" ::: "memory"); \
    __builtin_amdgcn_s_barrier();                      \
  } while (0)

// ---------------------------------------------------------------------------
// Coalesced weight repack. Old layout (aw/bw/p3w/f1w/f2w): 32k x 64n tiles,
// dest ((nc*KT+kt)*128 + nl)*32 + kk, CW=128. NEW layout (p1w/p2w only):
// 1KB chunk per (g=32-col group, kt, h=k-half16): elem(c, k16) at
// chunk + (c + 32*(k16>>3))*8 + (k16&7), chunk = ((g*KT+kt)*2+h)*512.
// ---------------------------------------------------------------------------
__global__ __launch_bounds__(256) void pack_lds(
    const float* __restrict__ aw, const float* __restrict__ bw,
    const float* __restrict__ p1w, const float* __restrict__ p2w,
    const float* __restrict__ p3w, const float* __restrict__ f1w,
    const float* __restrict__ f2w, bf16* __restrict__ wpk) {
  __shared__ float t[32][65];
  const int tid = threadIdx.x;
  int b = blockIdx.x;

  if (b < 550) {
    const float* src; int dstoff, K, N, tt;
    bool newf = false;
    if (b < 4)        { src = aw;  dstoff = WOFF_AW; K = 64;   N = 128;  tt = b; }
    else if (b < 6)   { src = bw;  dstoff = WOFF_BW; K = 32;   N = 128;  tt = b - 4; }
    else if (b < 102) { src = p1w; dstoff = WOFF_P1; K = 384;  N = 512;  tt = b - 6;   newf = true; }
    else if (b < 166) { src = p2w; dstoff = WOFF_P2; K = 512;  N = 256;  tt = b - 102; newf = true; }
    else if (b < 294) { src = p3w; dstoff = WOFF_P3; K = 256;  N = 1024; tt = b - 166; }
    else              { src = f1w; dstoff = WOFF_F1; K = 1024; N = 512;  tt = b - 294; }
    const int KT = K >> 5;
    const int kt = tt % KT;
    const int n0 = (tt / KT) * 64;
    for (int i = tid; i < 2048; i += 256) {
      int r = i >> 6, c = i & 63;
      t[r][c] = src[(size_t)(kt * 32 + r) * N + n0 + c];
    }
    __syncthreads();
    if (newf) {
      // new 32x32-MFMA layout
      const int cpp = tid & 63, rb = tid >> 6;      // col-in-64, k-oct
      const int g = (n0 >> 5) + (cpp >> 5);
      const int c = cpp & 31;
      bf16x8 v;
#pragma unroll
      for (int i = 0; i < 8; ++i) v[i] = (bf16)t[rb * 8 + i][cpp];
      *(bf16x8*)(wpk + dstoff +
                 (((size_t)g * KT + kt) * 2 + (rb >> 1)) * 512 +
                 (c + 32 * (rb & 1)) * 8) = v;
    } else {
      const int nc = n0 >> 7, nl0 = n0 & 127;
      bf16* dst = wpk + dstoff + ((size_t)(nc * KT + kt) * 128 + nl0) * 32;
      int o = tid * 8;
      int nl = o >> 5, kk = o & 31;
      bf16x8 v;
#pragma unroll
      for (int i = 0; i < 8; ++i) v[i] = (bf16)t[kk + i][nl];
      *(bf16x8*)(dst + nl * 32 + kk) = v;
    }
  } else {
    const int kt = b - 550;
    for (int i = tid; i < 1024; i += 256) {
      int r = i >> 5, c = i & 31;
      t[r][c] = f2w[(size_t)(kt * 32 + r) * 32 + c];
    }
    __syncthreads();
    if (tid < 128) {
      int o = tid * 8;
      int nl = o >> 5, kk = o & 31;
      bf16x8 v;
#pragma unroll
      for (int i = 0; i < 8; ++i) v[i] = (bf16)t[kk + i][nl];
      *(bf16x8*)(wpk + WOFF_F2 + kt * 1024 + nl * 32 + kk) = v;
    }
  }
}

// kstep, 2 B-frags from global: 4 A-reads, 8 MFMA (M=64) -- embed phase only
static __device__ __forceinline__ void kstep2(const bf16* __restrict__ Ab,
                                              int astride, int acol,
                                              const bf16* __restrict__ b0p,
                                              const bf16* __restrict__ b1p,
                                              floatx4* acc, int lm, int lq) {
  bf16x8 b0 = *(const bf16x8*)b0p;
  bf16x8 b1 = *(const bf16x8*)b1p;
#pragma unroll
  for (int mt = 0; mt < 4; ++mt) {
    bf16x8 a = *(const bf16x8*)(Ab + (mt * 16 + lm) * astride + acol + lq * 8);
    acc[mt * 2]     = mfma16(a, b0, acc[mt * 2]);
    acc[mt * 2 + 1] = mfma16(a, b1, acc[mt * 2 + 1]);
  }
}

// epilogue for 2-N-tile acc, pointer-bias version (embed only; 16x16 layout)
static __device__ __forceinline__ void epi2(const floatx4* acc,
                                            const float* __restrict__ bias,
                                            bf16* dst, int dstride, int w,
                                            int lm, int lq) {
#pragma unroll
  for (int mt = 0; mt < 4; ++mt)
#pragma unroll
    for (int j = 0; j < 2; ++j) {
      int col = (w + 4 * j) * 16 + lm;
      float bv = bias[col];
      floatx4 c = acc[mt * 2 + j];
#pragma unroll
      for (int r = 0; r < 4; ++r) {
        float v = c[r] + bv;
        v = v > 0.f ? v : 0.f;
        dst[(mt * 16 + lq * 4 + r) * dstride + col] = (bf16)v;
      }
    }
}

// ---------------------------------------------------------------------------
// seg_kernel: one block per 64-row WINDOW. Embed on 16x16 MFMA (compiler
// path); p1/p2 on 32x32x16 MFMA with the asm B-pipeline. Masked row-sums of
// h3 = relu(acc3+p2b) straight from registers -> hsum (f32). LDS 71680 B
// -> 2 blocks/CU.
// ---------------------------------------------------------------------------
__global__ __launch_bounds__(256, 2) void seg_kernel(
    const float* __restrict__ pairs, const float* __restrict__ ab,
    const float* __restrict__ bb, const float* __restrict__ p1b,
    const float* __restrict__ p2b, const bf16* __restrict__ wpk,
    float* __restrict__ hsum) {
  __shared__ __align__(16) bf16 hbuf[64 * LSTR_H];  // h[64,384]
  __shared__ __align__(16) bf16 pbuf[64 * LSTR_P];  // pairs bf16, then h2 chunk

  const int tid = threadIdx.x;
  const int w = tid >> 6;
  const int lane = tid & 63;
  const int lm = lane & 15;
  const int lq = lane >> 4;
  const int l31 = lane & 31;
  const int hi = lane >> 5;
  const int hi8 = hi * 8;
  const int ln8 = lane * 8;
  const int blk = blockIdx.x;

  // ---- stage pairs window [64,160] fp32 -> bf16 LDS (all rows valid) ----
  {
    const float4* src = (const float4*)(pairs + (size_t)blk * (64 * 160));
    for (int i = tid; i < 64 * 40; i += 256) {
      int row = i / 40;
      int c4 = (i - row * 40) * 4;
      float4 v = src[i];
      bf16x4 o = {(bf16)v.x, (bf16)v.y, (bf16)v.z, (bf16)v.w};
      *(bf16x4*)(pbuf + row * LSTR_P + c4) = o;
    }
  }
  SYNCL();

  const floatx4 fz = {0.f, 0.f, 0.f, 0.f};
  const floatx16 fz16 = {0.f, 0.f, 0.f, 0.f, 0.f, 0.f, 0.f, 0.f,
                         0.f, 0.f, 0.f, 0.f, 0.f, 0.f, 0.f, 0.f};
  floatx4 acc[8];

  // ---------------- embed: a1 / a2 / be -> hbuf[64,384] (16x16 path) ----
#pragma unroll
  for (int t = 0; t < 8; ++t) acc[t] = fz;
#pragma unroll
  for (int kt = 0; kt < 2; ++kt)
    kstep2(pbuf, LSTR_P, kt * 32,
           wpk + WOFF_AW + ((size_t)(kt * 128 + w * 16 + lm)) * 32 + lq * 8,
           wpk + WOFF_AW + ((size_t)(kt * 128 + (w + 4) * 16 + lm)) * 32 + lq * 8,
           acc, lm, lq);
  epi2(acc, ab, hbuf, LSTR_H, w, lm, lq);
#pragma unroll
  for (int t = 0; t < 8; ++t) acc[t] = fz;
#pragma unroll
  for (int kt = 0; kt < 2; ++kt)
    kstep2(pbuf, LSTR_P, 64 + kt * 32,
           wpk + WOFF_AW + ((size_t)(kt * 128 + w * 16 + lm)) * 32 + lq * 8,
           wpk + WOFF_AW + ((size_t)(kt * 128 + (w + 4) * 16 + lm)) * 32 + lq * 8,
           acc, lm, lq);
  epi2(acc, ab, hbuf + 128, LSTR_H, w, lm, lq);
#pragma unroll
  for (int t = 0; t < 8; ++t) acc[t] = fz;
  kstep2(pbuf, LSTR_P, 128,
         wpk + WOFF_BW + ((size_t)(w * 16 + lm)) * 32 + lq * 8,
         wpk + WOFF_BW + ((size_t)((w + 4) * 16 + lm)) * 32 + lq * 8,
         acc, lm, lq);
  epi2(acc, bb, hbuf + 256, LSTR_H, w, lm, lq);

  // ---- preload p1/p2 biases into registers (no vmem inside asm phases) ----
  // p1: wave col group gw = nc*4+w -> cols nc*128 + w*32 + l31 (one per nc)
  // p2: wave col groups {w, w+4} -> cols {w,w+4}*32 + l31
  float p1bv[4], p2bv[2];
#pragma unroll
  for (int nc = 0; nc < 4; ++nc) p1bv[nc] = p1b[nc * 128 + w * 32 + l31];
  p2bv[0] = p2b[w * 32 + l31];
  p2bv[1] = p2b[(w + 4) * 32 + l31];
  asm volatile("" : "+v"(p1bv[0]), "+v"(p1bv[1]), "+v"(p1bv[2]),
                    "+v"(p1bv[3]), "+v"(p2bv[0]), "+v"(p2bv[1]));

  floatx4 p1r0[4], p1r1[4];   // p1 B slots (4-slot, 3-kt lead; h=0 / h=1)
  floatx4 p2r[3][4];          // p2 B slots (3-slot; j = cg*2+h)
  floatx16 acc3[4];           // p2 out: [rg*2+cg], 64x64 per wave

  // prologue: nc=0 (gw=w) p1 chunks kt=0..2, h=0/1 -- in flight across SYNCL
#pragma unroll
  for (int q = 0; q < 3; ++q) {
    gload(p1r0[q], wpk + WOFF_P1 + (((size_t)w * 12 + q) * 2 + 0) * 512 + ln8);
    gload(p1r1[q], wpk + WOFF_P1 + (((size_t)w * 12 + q) * 2 + 1) * 512 + ln8);
  }
  SYNCL();   // hbuf visible; p1 B loads stay in flight

#pragma unroll
  for (int t = 0; t < 4; ++t) acc3[t] = fz16;

#pragma unroll
  for (int nc = 0; nc < 4; ++nc) {
    const int gw = nc * 4 + w;
    floatx16 acc2[2];
    acc2[0] = fz16; acc2[1] = fz16;

    // ---- p1: h[64,384] @ p1w cols gw*32..+32 (32x32x16) ----
    {
      bf16x8 an[2][4];   // [kt&1][rg*2+h]
#pragma unroll
      for (int q = 0; q < 2; ++q)
#pragma unroll
        for (int rg = 0; rg < 2; ++rg)
#pragma unroll
          for (int h = 0; h < 2; ++h)
            an[q][rg * 2 + h] = *(const bf16x8*)(
                hbuf + (rg * 32 + l31) * LSTR_H + q * 32 + h * 16 + hi8);
#pragma unroll
      for (int kt = 0; kt < 12; ++kt) {
        bf16x8 a00 = an[kt & 1][0], a01 = an[kt & 1][1];
        bf16x8 a10 = an[kt & 1][2], a11 = an[kt & 1][3];
        if (kt < 10) {
#pragma unroll
          for (int rg = 0; rg < 2; ++rg)
#pragma unroll
            for (int h = 0; h < 2; ++h)
              an[kt & 1][rg * 2 + h] = *(const bf16x8*)(
                  hbuf + (rg * 32 + l31) * LSTR_H + (kt + 2) * 32 + h * 16 + hi8);
        }
        if (kt < 9) {
          gload(p1r0[(kt + 3) & 3],
                wpk + WOFF_P1 + (((size_t)gw * 12 + kt + 3) * 2 + 0) * 512 + ln8);
          gload(p1r1[(kt + 3) & 3],
                wpk + WOFF_P1 + (((size_t)gw * 12 + kt + 3) * 2 + 1) * 512 + ln8);
        }
        if (kt < 9)       { VMW(6); }
        else if (kt == 9) { VMW(4); }
        else if (kt == 10){ VMW(2); }
        else              { VMW(0); }
        __builtin_amdgcn_s_setprio(1);
        bf16x8 b0 = bc8(p1r0[kt & 3]);
        bf16x8 b1 = bc8(p1r1[kt & 3]);
        acc2[0] = mfma32(a00, b0, acc2[0]);
        acc2[1] = mfma32(a10, b0, acc2[1]);
        acc2[0] = mfma32(a01, b1, acc2[0]);
        acc2[1] = mfma32(a11, b1, acc2[1]);
        __builtin_amdgcn_s_setprio(0);
      }
    }

    // issue p2 B for kt2=0,1 BEFORE the barriers: hidden under them + epi
#pragma unroll
    for (int q = 0; q < 2; ++q)
#pragma unroll
      for (int cg = 0; cg < 2; ++cg)
#pragma unroll
        for (int h = 0; h < 2; ++h)
          gload(p2r[q][cg * 2 + h],
                wpk + WOFF_P2 +
                    (((size_t)(cg ? w + 4 : w) * 16 + nc * 4 + q) * 2 + h) * 512 +
                    ln8);

    SYNCL();                       // prior p2 reads of pbuf done (lgkm only)
    // p1 epilogue: relu(acc2 + p1bv) -> pbuf h2 chunk, 32x32 C/D layout
    {
      float bv = p1bv[nc];
#pragma unroll
      for (int rg = 0; rg < 2; ++rg)
#pragma unroll
        for (int r = 0; r < 16; ++r) {
          float v = acc2[rg][r] + bv;
          v = v > 0.f ? v : 0.f;
          int row = rg * 32 + (r & 3) + 8 * (r >> 2) + 4 * hi;
          pbuf[row * LSTR_H2 + w * 32 + l31] = (bf16)v;
        }
    }
    SYNCL();                       // h2 chunk visible (lgkm only)

    // ---- p2: h2chunk[64,128] @ p2w chunk -> acc3 (32x32x16) ----
    {
      bf16x8 an2[2][4];   // [kt2&1][rg*2+h]
#pragma unroll
      for (int q = 0; q < 2; ++q)
#pragma unroll
        for (int rg = 0; rg < 2; ++rg)
#pragma unroll
          for (int h = 0; h < 2; ++h)
            an2[q][rg * 2 + h] = *(const bf16x8*)(
                pbuf + (rg * 32 + l31) * LSTR_H2 + q * 32 + h * 16 + hi8);
#pragma unroll
      for (int kt2 = 0; kt2 < 4; ++kt2) {
        bf16x8 ac[4];
#pragma unroll
        for (int f = 0; f < 4; ++f) ac[f] = an2[kt2 & 1][f];
        if (kt2 < 2) {
#pragma unroll
          for (int rg = 0; rg < 2; ++rg)
#pragma unroll
            for (int h = 0; h < 2; ++h)
              an2[kt2 & 1][rg * 2 + h] = *(const bf16x8*)(
                  pbuf + (rg * 32 + l31) * LSTR_H2 + (kt2 + 2) * 32 + h * 16 + hi8);
#pragma unroll
          for (int cg = 0; cg < 2; ++cg)
#pragma unroll
            for (int h = 0; h < 2; ++h)
              gload(p2r[(kt2 + 2) % 3][cg * 2 + h],
                    wpk + WOFF_P2 +
                        (((size_t)(cg ? w + 4 : w) * 16 + nc * 4 + kt2 + 2) * 2 + h) *
                            512 + ln8);
        }
        if (kt2 == 1) {
          const int gn = ((nc + 1) & 3) * 4 + w;
#pragma unroll
          for (int q = 0; q < 3; ++q) {
            gload(p1r0[q],
                  wpk + WOFF_P1 + (((size_t)gn * 12 + q) * 2 + 0) * 512 + ln8);
            gload(p1r1[q],
                  wpk + WOFF_P1 + (((size_t)gn * 12 + q) * 2 + 1) * 512 + ln8);
          }
        }
        if (kt2 == 0)      { VMW(8); }
        else if (kt2 == 1) { VMW(14); }
        else if (kt2 == 2) { VMW(10); }
        else               { VMW(6); }
        __builtin_amdgcn_s_setprio(1);
#pragma unroll
        for (int h = 0; h < 2; ++h) {
          bf16x8 b0 = bc8(p2r[kt2 % 3][0 * 2 + h]);
          bf16x8 b1 = bc8(p2r[kt2 % 3][1 * 2 + h]);
          acc3[0] = mfma32(ac[0 * 2 + h], b0, acc3[0]);   // rg0 cg0
          acc3[1] = mfma32(ac[0 * 2 + h], b1, acc3[1]);   // rg0 cg1
          acc3[2] = mfma32(ac[1 * 2 + h], b0, acc3[2]);   // rg1 cg0
          acc3[3] = mfma32(ac[1 * 2 + h], b1, acc3[3]);   // rg1 cg1
        }
        __builtin_amdgcn_s_setprio(0);
      }
    }
  }

  // ---- masked row-sums of h3 = relu(acc3 + p2b), 32x32 C/D layout ----
  // row = rg*32 + (r&3) + 8*(r>>2) + 4*hi; col = cg_col + l31.
  // Lanes l and l+32 hold complementary row halves of the same column ->
  // one shfl_xor(32) completes the column sum; lanes <32 store.
  const int s0 = (64 * blk) / 100;
  const int sp = (s0 + 1) * 100 - 64 * blk;

#pragma unroll
  for (int cg = 0; cg < 2; ++cg) {
    float bv = p2bv[cg];
    float tot = 0.f, cs0 = 0.f;
#pragma unroll
    for (int rg = 0; rg < 2; ++rg)
#pragma unroll
      for (int r = 0; r < 16; ++r) {
        float v = acc3[rg * 2 + cg][r] + bv;
        v = v > 0.f ? v : 0.f;
        tot += v;
        int row = rg * 32 + (r & 3) + 8 * (r >> 2) + 4 * hi;
        cs0 += (row < sp) ? v : 0.f;
      }
    float cs1 = tot - cs0;
    cs0 += __shfl_xor(cs0, 32, 64);
    cs1 += __shfl_xor(cs1, 32, 64);
    if (lane < 32) {
      int col = (cg ? w + 4 : w) * 32 + lane;
      hsum[(size_t)(2 * blk) * 256 + col]     = cs0;
      hsum[(size_t)(2 * blk + 1) * 256 + col] = cs1;
    }
  }
}

// ---------------------------------------------------------------------------
// tail_kernel: mid+head1+head2 fused. (byte-identical to v13-v16)
// ---------------------------------------------------------------------------
__global__ __launch_bounds__(512, 2) void tail_kernel(
    const bf16* __restrict__ wpk, const float* __restrict__ hsum,
    const int* __restrict__ idxp, const float* __restrict__ p3b,
    const float* __restrict__ f1b, const float* __restrict__ f2b,
    const float* __restrict__ f3w, const float* __restrict__ f3b,
    float* __restrict__ out) {
  __shared__ __align__(16) bf16 ms[16 * LSTR_MS];
  __shared__ __align__(16) bf16 hp[16 * 1032];
  __shared__ __align__(16) bf16 h2s[16 * 520];
  __shared__ __align__(16) bf16 h3s[16 * 40];

  const int tid = threadIdx.x;
  const int w = tid >> 6;          // 0..7
  const int lane = tid & 63;
  const int lm = lane & 15;
  const int lq = lane >> 4;
  const int r0 = blockIdx.x * 16;
  const floatx4 fz = {0.f, 0.f, 0.f, 0.f};

  for (int i = tid; i < 16 * 64; i += 512) {
    int row = i >> 6, c4 = i & 63;
    int seg = r0 + row;
    int b_lo = (100 * seg) >> 6;
    int b_hi = (100 * seg + 99) >> 6;
    float4 sa = {0.f, 0.f, 0.f, 0.f};
    for (int b = b_lo; b <= b_hi; ++b) {
      int slot = (64 * b >= 100 * seg) ? 0 : 1;
      float4 v = *(const float4*)(hsum + (size_t)(2 * b + slot) * 256 + c4 * 4);
      sa.x += v.x; sa.y += v.y; sa.z += v.z; sa.w += v.w;
    }
    float inv = 1.f / (float)idxp[seg];
    bf16x4 o = {(bf16)(sa.x * inv), (bf16)(sa.y * inv),
                (bf16)(sa.z * inv), (bf16)(sa.w * inv)};
    *(bf16x4*)(ms + row * LSTR_MS + c4 * 4) = o;
  }
  __syncthreads();

#pragma unroll
  for (int nt2 = 0; nt2 < 4; ++nt2) {
    floatx4 a2[2];
    a2[0] = fz; a2[1] = fz;
#pragma unroll
    for (int kt = 0; kt < 8; ++kt) {
      bf16x8 a = *(const bf16x8*)(ms + lm * LSTR_MS + kt * 32 + lq * 8);
#pragma unroll
      for (int j = 0; j < 2; ++j) {
        bf16x8 b = *(const bf16x8*)(wpk + WOFF_P3 +
            ((size_t)((w * 8 + kt) * 128 + (nt2 * 2 + j) * 16 + lm)) * 32 +
            lq * 8);
        a2[j] = mfma16(a, b, a2[j]);
      }
    }
#pragma unroll
    for (int j = 0; j < 2; ++j) {
      int col = w * 128 + (nt2 * 2 + j) * 16 + lm;
      float bv = p3b[col];
#pragma unroll
      for (int r = 0; r < 4; ++r)
        hp[(lq * 4 + r) * 1032 + col] = (bf16)(a2[j][r] + bv);
    }
  }
  __syncthreads();

  {
    floatx4 a4[4];
#pragma unroll
    for (int j = 0; j < 4; ++j) a4[j] = fz;
#pragma unroll 8
    for (int kt = 0; kt < 32; ++kt) {
      bf16x8 a = *(const bf16x8*)(hp + lm * 1032 + kt * 32 + lq * 8);
#pragma unroll
      for (int j = 0; j < 4; ++j) {
        bf16x8 b = *(const bf16x8*)(wpk + WOFF_F1 +
            ((size_t)(((w >> 1) * 32 + kt) * 128 + (w & 1) * 64 + j * 16 + lm)) * 32 +
            lq * 8);
        a4[j] = mfma16(a, b, a4[j]);
      }
    }
#pragma unroll
    for (int j = 0; j < 4; ++j) {
      int col = w * 64 + j * 16 + lm;
      float bv = f1b[col];
#pragma unroll
      for (int r = 0; r < 4; ++r) {
        float v = a4[j][r] + bv;
        v = v > 0.f ? v : 0.f;
        h2s[(lq * 4 + r) * 520 + col] = (bf16)v;
      }
    }
  }
  __syncthreads();

  if (w < 2) {
    floatx4 c2 = fz;
#pragma unroll
    for (int kt = 0; kt < 16; ++kt) {
      bf16x8 a = *(const bf16x8*)(h2s + lm * 520 + kt * 32 + lq * 8);
      bf16x8 b = *(const bf16x8*)(wpk + WOFF_F2 +
                    ((size_t)(kt * 32 + w * 16 + lm)) * 32 + lq * 8);
      c2 = mfma16(a, b, c2);
    }
    int col = w * 16 + lm;
    float bv = f2b[col];
#pragma unroll
    for (int r = 0; r < 4; ++r) {
      float v = c2[r] + bv;
      v = v > 0.f ? v : 0.f;
      h3s[(lq * 4 + r) * 40 + col] = (bf16)v;
    }
  }
  __syncthreads();
  if (w == 0) {
    float ps = 0.f;
#pragma unroll
    for (int jj = 0; jj < 8; ++jj)
      ps += (float)h3s[lm * 40 + lq * 8 + jj] * f3w[lq * 8 + jj];
    ps += __shfl_xor(ps, 16, 64);
    ps += __shfl_xor(ps, 32, 64);
    if (lq == 0) out[r0 + lm] = ps + f3b[0];
  }
}

// ---------------------------------------------------------------------------
extern "C" void kernel_launch(void* const* d_in, const int* in_sizes, int n_in,
                              void* d_out, int out_size, void* d_ws,
                              size_t ws_size, hipStream_t stream) {
  (void)in_sizes; (void)n_in; (void)out_size; (void)ws_size;
  const float* pairs = (const float*)d_in[0];
  const int*   idxp  = (const int*)d_in[1];
  // d_in[2] = ref_feats (unused by the reference)
  const float* aw  = (const float*)d_in[3];
  const float* ab  = (const float*)d_in[4];
  const float* bw  = (const float*)d_in[5];
  const float* bb  = (const float*)d_in[6];
  const float* p1w = (const float*)d_in[7];
  const float* p1b = (const float*)d_in[8];
  const float* p2w = (const float*)d_in[9];
  const float* p2b = (const float*)d_in[10];
  const float* p3w = (const float*)d_in[11];
  const float* p3b = (const float*)d_in[12];
  const float* f1w = (const float*)d_in[13];
  const float* f1b = (const float*)d_in[14];
  const float* f2w = (const float*)d_in[15];
  const float* f2b = (const float*)d_in[16];
  const float* f3w = (const float*)d_in[17];
  const float* f3b = (const float*)d_in[18];

  bf16* wpk = (bf16*)d_ws;
  float* hsum = (float*)(wpk + WOFF_HS);

  pack_lds<<<566, 256, 0, stream>>>(aw, bw, p1w, p2w, p3w, f1w, f2w, wpk);
  seg_kernel<<<NWIN, 256, 0, stream>>>(pairs, ab, bb, p1b, p2b, wpk, hsum);
  tail_kernel<<<125, 512, 0, stream>>>(wpk, hsum, idxp, p3b, f1b, f2b, f3w,
                                       f3b, (float*)d_out);
}